// Round 8
// baseline (367.009 us; speedup 1.0000x reference)
//
#include <hip/hip_runtime.h>
#include <hip/hip_bf16.h>

#define BB 2
#define HH 12
#define SS 4096
#define DD 768
#define HD 64
#define NBK 64
#define MC 3
#define LDK 72

typedef __attribute__((ext_vector_type(8))) short short8_t;
typedef __attribute__((ext_vector_type(4))) float float4_t;

__device__ __forceinline__ unsigned short f2bf(float f) {
  union { float f; unsigned u; } c;
  c.f = f;
  unsigned u = c.u + 0x7FFFu + ((c.u >> 16) & 1u);  // RNE
  return (unsigned short)(u >> 16);
}

// HW packed f32x2 -> bf16x2 (gfx950; RNE per HW default). 1 instr / 2 floats.
__device__ __forceinline__ unsigned cvtpk(float lo, float hi) {
  unsigned r;
  asm("v_cvt_pk_bf16_f32 %0, %1, %2" : "=v"(r) : "v"(lo), "v"(hi));
  return r;
}

// async 16B global -> LDS (gfx950). LDS dest = wave-uniform base + lane*16.
__device__ __forceinline__ void gload16(const unsigned short* gp,
                                        unsigned short* lp) {
  __builtin_amdgcn_global_load_lds(
      (const __attribute__((address_space(1))) unsigned int*)gp,
      (__attribute__((address_space(3))) unsigned int*)lp, 16, 0, 0);
}

// ---------------------------------------------------------------------------
// Convert-staging helpers: write fp32 regs as bf16 into the PROVEN swizzled
// layout (row r = 64 shorts = 8 chunks of 16B; chunk c at slot c^(r&7) ->
// measured 0 bank conflicts). A tile 128x64: thread t owns row t>>1, half
// t&1 (32 floats). B tile 64x64: thread t owns row t>>2, quarter t&3.
// ---------------------------------------------------------------------------
__device__ __forceinline__ void cvt_store_A(unsigned short* buf, int arow,
                                            int ah, const float4_t a4[8]) {
#pragma unroll
  for (int c2 = 0; c2 < 4; c2++) {
    int chunk = 4 * ah + c2;
    int slot = chunk ^ (arow & 7);
    uint4 wv;
    wv.x = cvtpk(a4[2 * c2][0], a4[2 * c2][1]);
    wv.y = cvtpk(a4[2 * c2][2], a4[2 * c2][3]);
    wv.z = cvtpk(a4[2 * c2 + 1][0], a4[2 * c2 + 1][1]);
    wv.w = cvtpk(a4[2 * c2 + 1][2], a4[2 * c2 + 1][3]);
    *(uint4*)&buf[arow * 64 + slot * 8] = wv;
  }
}

__device__ __forceinline__ void cvt_store_B(unsigned short* buf, int brow,
                                            int bq, const float4_t b4[4]) {
#pragma unroll
  for (int c2 = 0; c2 < 2; c2++) {
    int chunk = 2 * bq + c2;
    int slot = chunk ^ (brow & 7);
    uint4 wv;
    wv.x = cvtpk(b4[2 * c2][0], b4[2 * c2][1]);
    wv.y = cvtpk(b4[2 * c2][2], b4[2 * c2][3]);
    wv.z = cvtpk(b4[2 * c2 + 1][0], b4[2 * c2 + 1][1]);
    wv.w = cvtpk(b4[2 * c2 + 1][2], b4[2 * c2 + 1][3]);
    *(uint4*)&buf[brow * 64 + slot * 8] = wv;
  }
}

// ---------------------------------------------------------------------------
// GEMM core, fp32 inputs converted inline (cvt_all eliminated). Structure =
// round-0/6 proven: BM=128 BN=64 BK=64, dbuf, 1 barrier/iter. T14 split:
// loads for tile kt+64 issue right after the barrier (fly under MFMA),
// convert+ds_write lands in buf p^1 before the next barrier (attn2 pattern,
// race-free: readers of p^1 finished before this iter's top barrier).
// ---------------------------------------------------------------------------
template <int SWAP>
__device__ __forceinline__ void gemm_cvt_core(const float* Ab, const float* Bb,
                                              unsigned short* smem, int tid,
                                              float4_t acc[8]) {
  unsigned short* As = smem;          // 2 x 8192 shorts (32 KB)
  unsigned short* Bs = smem + 16384;  // 2 x 4096 shorts (16 KB)
  int lane = tid & 63, w = tid >> 6, wm = w * 32;
  int fr = lane & 15, qd = lane >> 4;
  int arow = tid >> 1, ah = tid & 1;
  int brow = tid >> 2, bq = tid & 3;
#pragma unroll
  for (int i = 0; i < 8; i++)
#pragma unroll
    for (int r = 0; r < 4; r++) acc[i][r] = 0.f;

  {  // prologue: tile 0 -> buf 0
    float4_t a4[8], b4[4];
#pragma unroll
    for (int u = 0; u < 8; u++) a4[u] = *(const float4_t*)(Ab + u * 4);
#pragma unroll
    for (int u = 0; u < 4; u++) b4[u] = *(const float4_t*)(Bb + u * 4);
    cvt_store_A(As, arow, ah, a4);
    cvt_store_B(Bs, brow, bq, b4);
  }
  int p = 0;
  for (int kt = 0; kt < DD; kt += 64) {
    __syncthreads();  // publishes buf p; all waves done reading buf p^1
    bool more = (kt + 64 < DD);
    float4_t a4[8], b4[4];
    if (more) {
#pragma unroll
      for (int u = 0; u < 8; u++)
        a4[u] = *(const float4_t*)(Ab + kt + 64 + u * 4);
#pragma unroll
      for (int u = 0; u < 4; u++)
        b4[u] = *(const float4_t*)(Bb + kt + 64 + u * 4);
    }
#pragma unroll
    for (int kk = 0; kk < 64; kk += 32) {
      int cb = qd + (kk >> 3);
      short8_t af[2], bfr[4];
#pragma unroll
      for (int i = 0; i < 2; i++) {
        int r_ = wm + i * 16 + fr;
        af[i] = *(const short8_t*)&As[p * 8192 + r_ * 64 + (cb ^ (fr & 7)) * 8];
      }
#pragma unroll
      for (int j = 0; j < 4; j++) {
        int r_ = j * 16 + fr;
        bfr[j] =
            *(const short8_t*)&Bs[p * 4096 + r_ * 64 + (cb ^ (fr & 7)) * 8];
      }
#pragma unroll
      for (int i = 0; i < 2; i++)
#pragma unroll
        for (int j = 0; j < 4; j++) {
          if (SWAP)
            acc[j * 2 + i] = __builtin_amdgcn_mfma_f32_16x16x32_bf16(
                bfr[j], af[i], acc[j * 2 + i], 0, 0, 0);
          else
            acc[i * 4 + j] = __builtin_amdgcn_mfma_f32_16x16x32_bf16(
                af[i], bfr[j], acc[i * 4 + j], 0, 0, 0);
        }
    }
    if (more) {
      cvt_store_A(As + (p ^ 1) * 8192, arow, ah, a4);
      cvt_store_B(Bs + (p ^ 1) * 4096, brow, bq, b4);
    }
    p ^= 1;
  }
}

// ---------------------------------------------------------------------------
// QKV projection straight from fp32 inputs. Q/K: swapped operands (C^T);
// V: normal, stored transposed into vtb[b][h][d][s]. Zeroes cnt[48] for the
// attn kernel's last-block reduction (kernel boundary orders it).
// ---------------------------------------------------------------------------
__global__ __launch_bounds__(256) void gemm_qkv_f(
    const float* __restrict__ hs, const float* __restrict__ Wq,
    const float* __restrict__ Wk, const float* __restrict__ Wv,
    unsigned short* __restrict__ qb, unsigned short* __restrict__ kb,
    unsigned short* __restrict__ vtb, int* __restrict__ cnt) {
  __shared__ __align__(16) unsigned short smem[24576];  // 48 KB
  int tid = threadIdx.x;
  if (blockIdx.x == 0 && blockIdx.y == 0 && tid < 48) cnt[tid] = 0;
  int m0 = blockIdx.x * 128;
  int n0 = blockIdx.y * 64;  // 64 | 768, never straddles
  int ysel = n0 / 768;
  int nb0 = n0 - ysel * 768;
  const float* Wsrc = (ysel == 0) ? Wq : (ysel == 1) ? Wk : Wv;
  int lane = tid & 63, w = tid >> 6, wm = w * 32;
  int arow = tid >> 1, ah = tid & 1;
  int brow = tid >> 2, bq = tid & 3;
  const float* Ab = hs + (size_t)(m0 + arow) * DD + ah * 32;
  const float* Bb = Wsrc + (size_t)(nb0 + brow) * DD + bq * 16;

  float4_t acc[8];
  if (ysel < 2) {
    gemm_cvt_core<1>(Ab, Bb, smem, tid, acc);
    int cn = lane & 15;
    int quad = lane >> 4;
    float scale = (ysel == 0) ? 0.125f : 1.0f;  // fold 1/sqrt(64) into Q
    unsigned short* dst = (ysel == 0) ? qb : kb;
#pragma unroll
    for (int j = 0; j < 4; j++)
#pragma unroll
      for (int i = 0; i < 2; i++) {
        int m = m0 + wm + i * 16 + cn;     // s dimension
        int nn = nb0 + j * 16 + quad * 4;  // d dimension (4-consec)
        int b = m >> 12, s = m & 4095;
        int h = nn >> 6, d0 = nn & 63;
        uint2 pk;
        pk.x = (unsigned)f2bf(acc[j * 2 + i][0] * scale) |
               ((unsigned)f2bf(acc[j * 2 + i][1] * scale) << 16);
        pk.y = (unsigned)f2bf(acc[j * 2 + i][2] * scale) |
               ((unsigned)f2bf(acc[j * 2 + i][3] * scale) << 16);
        *(uint2*)&dst[(((size_t)b * HH + h) * SS + s) * HD + d0] = pk;
      }
  } else {
    gemm_cvt_core<0>(Ab, Bb, smem, tid, acc);
    int cn = lane & 15;
    int quad = lane >> 4;
#pragma unroll
    for (int i = 0; i < 2; i++)
#pragma unroll
      for (int j = 0; j < 4; j++) {
        int m = m0 + wm + i * 16 + quad * 4;  // s base (4-consec)
        int nn = nb0 + j * 16 + cn;           // d dimension
        int b = m >> 12, s0 = m & 4095;
        int h = nn >> 6, d = nn & 63;
        uint2 pk;
        pk.x = (unsigned)f2bf(acc[i * 4 + j][0]) |
               ((unsigned)f2bf(acc[i * 4 + j][1]) << 16);
        pk.y = (unsigned)f2bf(acc[i * 4 + j][2]) |
               ((unsigned)f2bf(acc[i * 4 + j][3]) << 16);
        *(uint2*)&vtb[(((size_t)b * HH + h) * HD + d) * SS + s0] = pk;
      }
  }
}

// ---------------------------------------------------------------------------
// Output projection: A = ctxb (bf16) via proven gload16 staging; B = Wo
// (fp32) converted inline. fp32 output, coalesced.
// ---------------------------------------------------------------------------
__global__ __launch_bounds__(256) void gemm_out_f(
    const unsigned short* __restrict__ A, const float* __restrict__ Wo,
    float* __restrict__ dst) {
  __shared__ __align__(16) unsigned short smem[24576];
  unsigned short* As = smem;
  unsigned short* Bs = smem + 16384;
  int tid = threadIdx.x;
  int m0 = blockIdx.x * 128;
  int n0 = blockIdx.y * 64;
  int lane = tid & 63, w = tid >> 6, wm = w * 32;
  int fr = lane & 15, qd = lane >> 4;
  int brow = tid >> 2, bq = tid & 3;
  int rr = lane >> 3, cgx = (lane & 7) ^ rr;
  const float* Bb = Wo + (size_t)(n0 + brow) * DD + bq * 16;

  float4_t acc[8];
#pragma unroll
  for (int i = 0; i < 8; i++)
#pragma unroll
    for (int r = 0; r < 4; r++) acc[i][r] = 0.f;

  {  // prologue: tile 0
#pragma unroll
    for (int u = 0; u < 4; u++) {
      int g = w * 4 + u;
      gload16(A + (size_t)(m0 + g * 8 + rr) * DD + cgx * 8, &As[g * 512]);
    }
    float4_t b4[4];
#pragma unroll
    for (int u = 0; u < 4; u++) b4[u] = *(const float4_t*)(Bb + u * 4);
    cvt_store_B(Bs, brow, bq, b4);
  }
  int p = 0;
  for (int kt = 0; kt < DD; kt += 64) {
    __syncthreads();  // drains gload_lds of tile kt; publishes buf p
    bool more = (kt + 64 < DD);
    if (more) {
#pragma unroll
      for (int u = 0; u < 4; u++) {
        int g = w * 4 + u;
        gload16(A + (size_t)(m0 + g * 8 + rr) * DD + kt + 64 + cgx * 8,
                &As[(p ^ 1) * 8192 + g * 512]);
      }
    }
    float4_t b4[4];
    if (more) {
#pragma unroll
      for (int u = 0; u < 4; u++)
        b4[u] = *(const float4_t*)(Bb + kt + 64 + u * 4);
    }
#pragma unroll
    for (int kk = 0; kk < 64; kk += 32) {
      int cb = qd + (kk >> 3);
      short8_t af[2], bfr[4];
#pragma unroll
      for (int i = 0; i < 2; i++) {
        int r_ = wm + i * 16 + fr;
        af[i] = *(const short8_t*)&As[p * 8192 + r_ * 64 + (cb ^ (fr & 7)) * 8];
      }
#pragma unroll
      for (int j = 0; j < 4; j++) {
        int r_ = j * 16 + fr;
        bfr[j] =
            *(const short8_t*)&Bs[p * 4096 + r_ * 64 + (cb ^ (fr & 7)) * 8];
      }
#pragma unroll
      for (int i = 0; i < 2; i++)
#pragma unroll
        for (int j = 0; j < 4; j++)
          acc[i * 4 + j] = __builtin_amdgcn_mfma_f32_16x16x32_bf16(
              af[i], bfr[j], acc[i * 4 + j], 0, 0, 0);
    }
    if (more) cvt_store_B(Bs + (p ^ 1) * 4096, brow, bq, b4);
    p ^= 1;
  }

  int cn = lane & 15;
  int rb = (lane >> 4) * 4;
#pragma unroll
  for (int i = 0; i < 2; i++)
#pragma unroll
    for (int j = 0; j < 4; j++)
#pragma unroll
      for (int r = 0; r < 4; r++) {
        int m = m0 + wm + i * 16 + rb + r;
        int n = n0 + j * 16 + cn;
        dst[(size_t)m * DD + n] = acc[i * 4 + j][r];
      }
}

// ---------------------------------------------------------------------------
// Block-sparse attention + FUSED heavy reduction (last-chunk block reduces:
// __threadfence release + device-scope atomicAdd on cnt[hid], m20).
// Grid: ids 0..383 heavy chunks, 384..1871 lights.
// ---------------------------------------------------------------------------
__global__ __launch_bounds__(256) void attn2r(
    const unsigned short* __restrict__ q, const unsigned short* __restrict__ k,
    const unsigned short* __restrict__ vt, const int* __restrict__ graph,
    unsigned short* __restrict__ ctxb, float* __restrict__ part,
    int* __restrict__ cnt) {
  __shared__ unsigned short Ks[2][64 * LDK];
  __shared__ unsigned short Vs[2][64 * LDK];
  __shared__ unsigned short Ps[4][16 * LDK];
  __shared__ int isLast;

  int tid = threadIdx.x;
  int id = blockIdx.x;
  int b, h, l, nkb, heavy, chunk = 0, hid = 0;
  int list[8];
  if (id < 384) {
    heavy = 1;
    hid = id >> 3;
    chunk = id & 7;
    b = hid / 24;
    int r = hid % 24;
    h = r >> 1;
    l = (r & 1) ? (NBK - 1) : 0;
    nkb = 8;
#pragma unroll
    for (int i = 0; i < 8; i++) list[i] = chunk * 8 + i;
  } else {
    heavy = 0;
    int j = id - 384;
    b = j / 744;  // 744 = 12*62
    int r = j % 744;
    h = r / 62;
    l = 1 + r % 62;
    const int* g = graph + (((size_t)b * HH + h) * NBK + l) * MC;
    int n = 0;
    if (l == 1) {
      list[0] = 0; list[1] = 1; list[2] = 2; list[3] = NBK - 1; n = 4;
    } else if (l == NBK - 2) {
      list[0] = 0; list[1] = NBK - 3; list[2] = NBK - 2; list[3] = NBK - 1;
      n = 4;
    } else {
      list[0] = 0; list[1] = l - 1; list[2] = l; list[3] = l + 1;
      list[4] = NBK - 1; n = 5;
    }
    for (int m = 0; m < MC; m++) list[n++] = g[m];
    nkb = n;
  }
  size_t base = ((size_t)b * HH + h) * SS * HD;

  int lane = tid & 63;
  int w = tid >> 6;
  int lr = lane & 15;
  int quad = lane >> 4;

  short8_t qa[2];
  {
    const unsigned short* qp =
        q + base + (size_t)(l * 64 + w * 16 + lr) * HD + quad * 8;
    qa[0] = *(const short8_t*)qp;
    qa[1] = *(const short8_t*)(qp + 32);
  }

  float4_t Ot[4];
  float ls[4];
#pragma unroll
  for (int t = 0; t < 4; t++)
#pragma unroll
    for (int r = 0; r < 4; r++) Ot[t][r] = 0.f;
#pragma unroll
  for (int r = 0; r < 4; r++) ls[r] = 0.f;

  int srow = tid >> 3;
  int scol = (tid & 7) * 8;

  uint4 kr0, kr1, vr0, vr1;
  {
    int kb = list[0];
    const unsigned short* kp = k + base + (size_t)(kb * 64 + srow) * HD + scol;
    const unsigned short* vp = vt + base + (size_t)srow * SS + kb * 64 + scol;
    kr0 = *(const uint4*)kp;
    kr1 = *(const uint4*)(kp + 32 * HD);
    vr0 = *(const uint4*)vp;
    vr1 = *(const uint4*)(vp + 32 * SS);
  }
  *(uint4*)&Ks[0][srow * LDK + scol] = kr0;
  *(uint4*)&Ks[0][(srow + 32) * LDK + scol] = kr1;
  *(uint4*)&Vs[0][srow * LDK + scol] = vr0;
  *(uint4*)&Vs[0][(srow + 32) * LDK + scol] = vr1;
  int p = 0;

  for (int t = 0; t < nkb; t++) {
    __syncthreads();

    if (t + 1 < nkb) {
      int kb = list[t + 1];
      const unsigned short* kp =
          k + base + (size_t)(kb * 64 + srow) * HD + scol;
      const unsigned short* vp =
          vt + base + (size_t)srow * SS + kb * 64 + scol;
      kr0 = *(const uint4*)kp;
      kr1 = *(const uint4*)(kp + 32 * HD);
      vr0 = *(const uint4*)vp;
      vr1 = *(const uint4*)(vp + 32 * SS);
    }

    float4_t st[4];
#pragma unroll
    for (int tt = 0; tt < 4; tt++) {
#pragma unroll
      for (int r = 0; r < 4; r++) st[tt][r] = 0.f;
      short8_t kb0 = *(const short8_t*)&Ks[p][(tt * 16 + lr) * LDK + quad * 8];
      short8_t kb1 =
          *(const short8_t*)&Ks[p][(tt * 16 + lr) * LDK + quad * 8 + 32];
      st[tt] =
          __builtin_amdgcn_mfma_f32_16x16x32_bf16(qa[0], kb0, st[tt], 0, 0, 0);
      st[tt] =
          __builtin_amdgcn_mfma_f32_16x16x32_bf16(qa[1], kb1, st[tt], 0, 0, 0);
    }

#pragma unroll
    for (int tt = 0; tt < 4; tt++)
#pragma unroll
      for (int r = 0; r < 4; r++) {
        float pv = __expf(st[tt][r]);
        st[tt][r] = pv;
        ls[r] += pv;
        Ps[w][(quad * 4 + r) * LDK + tt * 16 + lr] = f2bf(pv);
      }

#pragma unroll
    for (int s = 0; s < 2; s++) {
      short8_t pa = *(const short8_t*)&Ps[w][lr * LDK + s * 32 + quad * 8];
#pragma unroll
      for (int tt = 0; tt < 4; tt++) {
        short8_t vb =
            *(const short8_t*)&Vs[p][(tt * 16 + lr) * LDK + s * 32 + quad * 8];
        Ot[tt] =
            __builtin_amdgcn_mfma_f32_16x16x32_bf16(pa, vb, Ot[tt], 0, 0, 0);
      }
    }

    if (t + 1 < nkb) {
      *(uint4*)&Ks[p ^ 1][srow * LDK + scol] = kr0;
      *(uint4*)&Ks[p ^ 1][(srow + 32) * LDK + scol] = kr1;
      *(uint4*)&Vs[p ^ 1][srow * LDK + scol] = vr0;
      *(uint4*)&Vs[p ^ 1][(srow + 32) * LDK + scol] = vr1;
    }
    p ^= 1;
  }

#pragma unroll
  for (int r = 0; r < 4; r++)
#pragma unroll
    for (int off = 1; off < 16; off <<= 1) ls[r] += __shfl_xor(ls[r], off);

  if (!heavy) {
#pragma unroll
    for (int r = 0; r < 4; r++) {
      float inv = 1.f / ls[r];
      size_t row = (size_t)b * SS + (size_t)l * 64 + w * 16 + quad * 4 + r;
#pragma unroll
      for (int tt = 0; tt < 4; tt++)
        ctxb[row * DD + h * HD + tt * 16 + lr] = f2bf(Ot[tt][r] * inv);
    }
    return;
  }

  // ---- heavy: write partials, then last-arriving chunk reduces ----
  float* pb = part + ((size_t)hid * 8 + chunk) * 4160;  // 64*64 O + 64 lsum
#pragma unroll
  for (int r = 0; r < 4; r++) {
    int rowi = w * 16 + quad * 4 + r;
#pragma unroll
    for (int tt = 0; tt < 4; tt++) pb[rowi * 64 + tt * 16 + lr] = Ot[tt][r];
    if (lr == 0) pb[4096 + rowi] = ls[r];
  }
  __threadfence();   // release: this thread's partials visible device-wide
  __syncthreads();   // all threads of the block fenced
  if (tid == 0) isLast = (atomicAdd(&cnt[hid], 1) == 7);
  __syncthreads();
  if (isLast) {
    __threadfence();  // acquire: other chunks' partials now visible
    float* lrow = (float*)&Ks[0][0];  // LDS reuse (compute fully done)
    const float* pbase = part + (size_t)hid * 8 * 4160;
    if (tid < 64) {
      float s = 0.f;
#pragma unroll
      for (int c = 0; c < 8; c++) s += pbase[c * 4160 + 4096 + tid];
      lrow[tid] = s;
    }
    __syncthreads();
    for (int e = tid; e < 4096; e += 256) {
      float o = 0.f;
#pragma unroll
      for (int c = 0; c < 8; c++) o += pbase[c * 4160 + e];
      int rowi = e >> 6, col = e & 63;
      size_t row = (size_t)b * SS + (size_t)l * 64 + rowi;
      ctxb[row * DD + h * HD + col] = f2bf(o / lrow[rowi]);
    }
  }
}

extern "C" void kernel_launch(void* const* d_in, const int* in_sizes, int n_in,
                              void* d_out, int out_size, void* d_ws,
                              size_t ws_size, hipStream_t stream) {
  const float* hs = (const float*)d_in[0];
  const float* Wq = (const float*)d_in[1];
  const float* Wk = (const float*)d_in[2];
  const float* Wv = (const float*)d_in[3];
  const float* Wo = (const float*)d_in[4];
  const int* graph = (const int*)d_in[10];

  const size_t NHS = (size_t)BB * SS * DD;  // 6291456
  unsigned short* qb = (unsigned short*)d_ws;
  unsigned short* kb = qb + NHS;
  unsigned short* vtb = kb + NHS;
  unsigned short* ctxb = vtb + NHS;
  float* part = (float*)(ctxb + NHS);      // 48*8*4160 floats
  int* cnt = (int*)(part + 48 * 8 * 4160); // 48 ints

  gemm_qkv_f<<<dim3(64, 36, 1), 256, 0, stream>>>(hs, Wq, Wk, Wv, qb, kb, vtb,
                                                  cnt);
  attn2r<<<1872, 256, 0, stream>>>(qb, kb, vtb, graph, ctxb, part, cnt);
  gemm_out_f<<<dim3(64, 12, 1), 256, 0, stream>>>(ctxb, Wo, (float*)d_out);
}

// Round 9
// 275.660 us; speedup vs baseline: 1.3314x; 1.3314x over previous
//
#include <hip/hip_runtime.h>
#include <hip/hip_bf16.h>

#define BB 2
#define HH 12
#define SS 4096
#define DD 768
#define HD 64
#define NBK 64
#define MC 3
#define LDK 72

typedef __attribute__((ext_vector_type(8))) short short8_t;
typedef __attribute__((ext_vector_type(4))) float float4_t;

__device__ __forceinline__ unsigned short f2bf(float f) {
  union { float f; unsigned u; } c;
  c.f = f;
  unsigned u = c.u + 0x7FFFu + ((c.u >> 16) & 1u);  // RNE
  return (unsigned short)(u >> 16);
}

// async 16B global -> LDS (gfx950). LDS dest = wave-uniform base + lane*16.
__device__ __forceinline__ void gload16(const unsigned short* gp,
                                        unsigned short* lp) {
  __builtin_amdgcn_global_load_lds(
      (const __attribute__((address_space(1))) unsigned int*)gp,
      (__attribute__((address_space(3))) unsigned int*)lp, 16, 0, 0);
}

// ---------------------------------------------------------------------------
// One-shot fp32 -> bf16 conversion (kept separate: round 8 proved inline
// conversion triples GEMM fetch traffic — bf16 staging pays for itself).
// Also zeroes cnt[48] for attn2r's last-block reduction.
// ---------------------------------------------------------------------------
__global__ __launch_bounds__(256) void cvt_all(
    const float* __restrict__ hs, const float* __restrict__ Wq,
    const float* __restrict__ Wk, const float* __restrict__ Wv,
    const float* __restrict__ Wo, unsigned short* __restrict__ hsb,
    unsigned short* __restrict__ wqkvb, unsigned short* __restrict__ wob,
    int* __restrict__ cnt) {
  if (blockIdx.x == 0 && threadIdx.x < 48) cnt[threadIdx.x] = 0;
  long i4 = (long)blockIdx.x * 256 + threadIdx.x;  // float4 index
  const float* src;
  unsigned short* dst;
  if (i4 < 1572864) {          // hs: 6291456 floats
    src = hs + i4 * 4;
    dst = hsb + i4 * 4;
  } else {
    long r = i4 - 1572864;
    int w = (int)(r / 147456);  // 0..3 : Wq,Wk,Wv,Wo (589824 floats each)
    long e = r % 147456;
    src = (w == 0 ? Wq : w == 1 ? Wk : w == 2 ? Wv : Wo) + e * 4;
    dst = (w < 3) ? (wqkvb + (long)w * 589824 + e * 4) : (wob + e * 4);
  }
  float4_t v = *(const float4_t*)src;
  uint2 p;
  p.x = (unsigned)f2bf(v[0]) | ((unsigned)f2bf(v[1]) << 16);
  p.y = (unsigned)f2bf(v[2]) | ((unsigned)f2bf(v[3]) << 16);
  *(uint2*)dst = p;
}

// ---------------------------------------------------------------------------
// GEMM (round-6 proven): BM=128 BN=64 BK=64, dbuf, 1 barrier/iter, XOR
// swizzle slot=c^(r&7) (measured 0 bank conflicts), gload_lds staging,
// 48 KB LDS -> 3 blocks/CU. Plain __launch_bounds__(256) (min-wave hints
// clamp VGPR below the accumulator and spill — rounds 2/3).
// ---------------------------------------------------------------------------
#define STAGE_T(buf_, A_, B_, m0_, n0_, kt_)                                  \
  {                                                                           \
    int rr_ = lane >> 3;                                                      \
    int cg_ = (lane & 7) ^ rr_;                                               \
    _Pragma("unroll") for (int u = 0; u < 4; u++) {                           \
      int g_ = w * 4 + u;                                                     \
      gload16(A_ + (size_t)(m0_ + g_ * 8 + rr_) * DD + kt_ + cg_ * 8,         \
              &As[buf_][g_ * 512]);                                           \
    }                                                                         \
    _Pragma("unroll") for (int u = 0; u < 2; u++) {                           \
      int g_ = w * 2 + u;                                                     \
      gload16(B_ + (size_t)(n0_ + g_ * 8 + rr_) * DD + kt_ + cg_ * 8,         \
              &Bs[buf_][g_ * 512]);                                           \
    }                                                                         \
  }

#define LOAD_FRAGS2(buf_, kk_)                                                \
  int cb = qd + ((kk_) >> 3);                                                 \
  short8_t af[2], bfr[4];                                                     \
  _Pragma("unroll") for (int i = 0; i < 2; i++) {                             \
    int r_ = wm + i * 16 + fr;                                                \
    af[i] = *(const short8_t*)&As[buf_][r_ * 64 + (cb ^ (fr & 7)) * 8];       \
  }                                                                           \
  _Pragma("unroll") for (int j = 0; j < 4; j++) {                             \
    int r_ = j * 16 + fr;                                                     \
    bfr[j] = *(const short8_t*)&Bs[buf_][r_ * 64 + (cb ^ (fr & 7)) * 8];      \
  }

__global__ __launch_bounds__(256) void gemm_qkv_b(
    const unsigned short* __restrict__ A, const unsigned short* __restrict__ W,
    unsigned short* __restrict__ qb, unsigned short* __restrict__ kb,
    unsigned short* __restrict__ vtb) {
  __shared__ unsigned short As[2][128 * 64];  // 32 KB
  __shared__ unsigned short Bs[2][64 * 64];   // 16 KB
  int tid = threadIdx.x;
  int m0 = blockIdx.x * 128;
  int n0 = blockIdx.y * 64;   // 64 | 768 so never straddles
  int lane = tid & 63;
  int w = tid >> 6;
  int wm = w * 32;            // 4 waves x 32 rows; all waves span 64 cols
  int fr = lane & 15;
  int qd = lane >> 4;
  int ysel = n0 / 768;

  float4_t acc[8];
#pragma unroll
  for (int i = 0; i < 8; i++)
#pragma unroll
    for (int r = 0; r < 4; r++) acc[i][r] = 0.f;

  STAGE_T(0, A, W, m0, n0, 0)
  int p = 0;

  if (ysel < 2) {
    // ---- Q/K: swapped-operand K-loop; acc[j*2+i] = C^T tile ----
    for (int kt = 0; kt < DD; kt += 64) {
      __syncthreads();  // drains stage(kt); waves done reading buf p^1
      if (kt + 64 < DD) STAGE_T(p ^ 1, A, W, m0, n0, kt + 64)
#pragma unroll
      for (int kk = 0; kk < 64; kk += 32) {
        LOAD_FRAGS2(p, kk)
#pragma unroll
        for (int i = 0; i < 2; i++)
#pragma unroll
          for (int j = 0; j < 4; j++)
            acc[j * 2 + i] = __builtin_amdgcn_mfma_f32_16x16x32_bf16(
                bfr[j], af[i], acc[j * 2 + i], 0, 0, 0);
      }
      p ^= 1;
    }
    int cn = lane & 15;
    int quad = lane >> 4;
    float scale = (ysel == 0) ? 0.125f : 1.0f;  // fold 1/sqrt(64) into Q
    unsigned short* dst = (ysel == 0) ? qb : kb;
    int nb0 = n0 - ysel * 768;
#pragma unroll
    for (int j = 0; j < 4; j++)
#pragma unroll
      for (int i = 0; i < 2; i++) {
        int m = m0 + wm + i * 16 + cn;         // s dimension
        int nn = nb0 + j * 16 + quad * 4;      // d dimension (4-consec)
        int b = m >> 12, s = m & 4095;
        int h = nn >> 6, d0 = nn & 63;
        uint2 pk;
        pk.x = (unsigned)f2bf(acc[j * 2 + i][0] * scale) |
               ((unsigned)f2bf(acc[j * 2 + i][1] * scale) << 16);
        pk.y = (unsigned)f2bf(acc[j * 2 + i][2] * scale) |
               ((unsigned)f2bf(acc[j * 2 + i][3] * scale) << 16);
        *(uint2*)&dst[(((size_t)b * HH + h) * SS + s) * HD + d0] = pk;
      }
  } else {
    // ---- V: normal K-loop; reg dim spans s (contig in [b][h][d][s]) ----
    for (int kt = 0; kt < DD; kt += 64) {
      __syncthreads();
      if (kt + 64 < DD) STAGE_T(p ^ 1, A, W, m0, n0, kt + 64)
#pragma unroll
      for (int kk = 0; kk < 64; kk += 32) {
        LOAD_FRAGS2(p, kk)
#pragma unroll
        for (int i = 0; i < 2; i++)
#pragma unroll
          for (int j = 0; j < 4; j++)
            acc[i * 4 + j] = __builtin_amdgcn_mfma_f32_16x16x32_bf16(
                af[i], bfr[j], acc[i * 4 + j], 0, 0, 0);
      }
      p ^= 1;
    }
    int cn = lane & 15;
    int quad = lane >> 4;
    int nb0 = n0 - 1536;
#pragma unroll
    for (int i = 0; i < 2; i++)
#pragma unroll
      for (int j = 0; j < 4; j++) {
        int m = m0 + wm + i * 16 + quad * 4;   // s base (4-consec)
        int nn = nb0 + j * 16 + cn;            // d dimension
        int b = m >> 12, s0 = m & 4095;
        int h = nn >> 6, d = nn & 63;
        uint2 pk;
        pk.x = (unsigned)f2bf(acc[i * 4 + j][0]) |
               ((unsigned)f2bf(acc[i * 4 + j][1]) << 16);
        pk.y = (unsigned)f2bf(acc[i * 4 + j][2]) |
               ((unsigned)f2bf(acc[i * 4 + j][3]) << 16);
        *(uint2*)&vtb[(((size_t)b * HH + h) * HD + d) * SS + s0] = pk;
      }
  }
}

__global__ __launch_bounds__(256) void gemm_out_b(
    const unsigned short* __restrict__ A, const unsigned short* __restrict__ W,
    float* __restrict__ dst) {
  __shared__ unsigned short As[2][128 * 64];
  __shared__ unsigned short Bs[2][64 * 64];
  int tid = threadIdx.x;
  int m0 = blockIdx.x * 128;
  int n0 = blockIdx.y * 64;
  int lane = tid & 63;
  int w = tid >> 6;
  int wm = w * 32;
  int fr = lane & 15;
  int qd = lane >> 4;

  float4_t acc[8];
#pragma unroll
  for (int i = 0; i < 8; i++)
#pragma unroll
    for (int r = 0; r < 4; r++) acc[i][r] = 0.f;

  STAGE_T(0, A, W, m0, n0, 0)
  int p = 0;
  for (int kt = 0; kt < DD; kt += 64) {
    __syncthreads();
    if (kt + 64 < DD) STAGE_T(p ^ 1, A, W, m0, n0, kt + 64)
#pragma unroll
    for (int kk = 0; kk < 64; kk += 32) {
      LOAD_FRAGS2(p, kk)
#pragma unroll
      for (int i = 0; i < 2; i++)
#pragma unroll
        for (int j = 0; j < 4; j++)
          acc[i * 4 + j] = __builtin_amdgcn_mfma_f32_16x16x32_bf16(
              af[i], bfr[j], acc[i * 4 + j], 0, 0, 0);
    }
    p ^= 1;
  }

  int cn = lane & 15;
  int rb = (lane >> 4) * 4;
#pragma unroll
  for (int i = 0; i < 2; i++)
#pragma unroll
    for (int j = 0; j < 4; j++)
#pragma unroll
      for (int r = 0; r < 4; r++) {
        int m = m0 + wm + i * 16 + rb + r;
        int n = n0 + j * 16 + cn;
        dst[(size_t)m * DD + n] = acc[i * 4 + j][r];
      }
}

// ---------------------------------------------------------------------------
// Block-sparse attention + FUSED heavy reduction (proven in round 8):
// heavy chunks write partials, __threadfence release, device-scope
// atomicAdd(cnt[hid]); 8th arrival reduces in-place (m20 last-block).
// Grid: ids 0..383 heavy chunks, 384..1871 lights.
// ---------------------------------------------------------------------------
__global__ __launch_bounds__(256) void attn2r(
    const unsigned short* __restrict__ q, const unsigned short* __restrict__ k,
    const unsigned short* __restrict__ vt, const int* __restrict__ graph,
    unsigned short* __restrict__ ctxb, float* __restrict__ part,
    int* __restrict__ cnt) {
  __shared__ unsigned short Ks[2][64 * LDK];   // K[key][d]
  __shared__ unsigned short Vs[2][64 * LDK];   // V^T[d][key]
  __shared__ unsigned short Ps[4][16 * LDK];   // per-wave P[q][key]
  __shared__ int isLast;

  int tid = threadIdx.x;
  int id = blockIdx.x;
  int b, h, l, nkb, heavy, chunk = 0, hid = 0;
  int list[8];
  if (id < 384) {
    heavy = 1;
    hid = id >> 3;
    chunk = id & 7;
    b = hid / 24;
    int r = hid % 24;
    h = r >> 1;
    l = (r & 1) ? (NBK - 1) : 0;
    nkb = 8;
#pragma unroll
    for (int i = 0; i < 8; i++) list[i] = chunk * 8 + i;
  } else {
    heavy = 0;
    int j = id - 384;
    b = j / 744;  // 744 = 12*62
    int r = j % 744;
    h = r / 62;
    l = 1 + r % 62;
    const int* g = graph + (((size_t)b * HH + h) * NBK + l) * MC;
    int n = 0;
    if (l == 1) {
      list[0] = 0; list[1] = 1; list[2] = 2; list[3] = NBK - 1; n = 4;
    } else if (l == NBK - 2) {
      list[0] = 0; list[1] = NBK - 3; list[2] = NBK - 2; list[3] = NBK - 1;
      n = 4;
    } else {
      list[0] = 0; list[1] = l - 1; list[2] = l; list[3] = l + 1;
      list[4] = NBK - 1; n = 5;
    }
    for (int m = 0; m < MC; m++) list[n++] = g[m];
    nkb = n;
  }
  size_t base = ((size_t)b * HH + h) * SS * HD;

  int lane = tid & 63;
  int w = tid >> 6;
  int lr = lane & 15;     // fragment m/n index
  int quad = lane >> 4;   // fragment k-group

  // Q fragments (A-layout) straight from global (q pre-scaled).
  short8_t qa[2];
  {
    const unsigned short* qp =
        q + base + (size_t)(l * 64 + w * 16 + lr) * HD + quad * 8;
    qa[0] = *(const short8_t*)qp;
    qa[1] = *(const short8_t*)(qp + 32);
  }

  float4_t Ot[4];
  float ls[4];
#pragma unroll
  for (int t = 0; t < 4; t++)
#pragma unroll
    for (int r = 0; r < 4; r++) Ot[t][r] = 0.f;
#pragma unroll
  for (int r = 0; r < 4; r++) ls[r] = 0.f;

  // staging: each thread moves 2x16B for K and 2x16B for Vt
  int srow = tid >> 3;          // 0..31
  int scol = (tid & 7) * 8;     // 0..56

  uint4 kr0, kr1, vr0, vr1;
  {
    int kb = list[0];
    const unsigned short* kp = k + base + (size_t)(kb * 64 + srow) * HD + scol;
    const unsigned short* vp = vt + base + (size_t)srow * SS + kb * 64 + scol;
    kr0 = *(const uint4*)kp;
    kr1 = *(const uint4*)(kp + 32 * HD);
    vr0 = *(const uint4*)vp;
    vr1 = *(const uint4*)(vp + 32 * SS);
  }
  *(uint4*)&Ks[0][srow * LDK + scol] = kr0;
  *(uint4*)&Ks[0][(srow + 32) * LDK + scol] = kr1;
  *(uint4*)&Vs[0][srow * LDK + scol] = vr0;
  *(uint4*)&Vs[0][(srow + 32) * LDK + scol] = vr1;
  int p = 0;

  for (int t = 0; t < nkb; t++) {
    __syncthreads();  // buf[p] writes visible; all waves done reading buf[p^1]

    if (t + 1 < nkb) {  // issue next block's global loads (fly during compute)
      int kb = list[t + 1];
      const unsigned short* kp =
          k + base + (size_t)(kb * 64 + srow) * HD + scol;
      const unsigned short* vp =
          vt + base + (size_t)srow * SS + kb * 64 + scol;
      kr0 = *(const uint4*)kp;
      kr1 = *(const uint4*)(kp + 32 * HD);
      vr0 = *(const uint4*)vp;
      vr1 = *(const uint4*)(vp + 32 * SS);
    }

    // S = Q K^T
    float4_t st[4];
#pragma unroll
    for (int tt = 0; tt < 4; tt++) {
#pragma unroll
      for (int r = 0; r < 4; r++) st[tt][r] = 0.f;
      short8_t kb0 = *(const short8_t*)&Ks[p][(tt * 16 + lr) * LDK + quad * 8];
      short8_t kb1 =
          *(const short8_t*)&Ks[p][(tt * 16 + lr) * LDK + quad * 8 + 32];
      st[tt] =
          __builtin_amdgcn_mfma_f32_16x16x32_bf16(qa[0], kb0, st[tt], 0, 0, 0);
      st[tt] =
          __builtin_amdgcn_mfma_f32_16x16x32_bf16(qa[1], kb1, st[tt], 0, 0, 0);
    }

    // fixed-max softmax: p = exp(s); per-lane partial sums, no shuffles.
#pragma unroll
    for (int tt = 0; tt < 4; tt++)
#pragma unroll
      for (int r = 0; r < 4; r++) {
        float pv = __expf(st[tt][r]);
        st[tt][r] = pv;
        ls[r] += pv;
        Ps[w][(quad * 4 + r) * LDK + tt * 16 + lr] = f2bf(pv);
      }

    // O += P V
#pragma unroll
    for (int s = 0; s < 2; s++) {
      short8_t pa = *(const short8_t*)&Ps[w][lr * LDK + s * 32 + quad * 8];
#pragma unroll
      for (int tt = 0; tt < 4; tt++) {
        short8_t vb =
            *(const short8_t*)&Vs[p][(tt * 16 + lr) * LDK + s * 32 + quad * 8];
        Ot[tt] =
            __builtin_amdgcn_mfma_f32_16x16x32_bf16(pa, vb, Ot[tt], 0, 0, 0);
      }
    }

    if (t + 1 < nkb) {  // write prefetched regs into the other buffer
      *(uint4*)&Ks[p ^ 1][srow * LDK + scol] = kr0;
      *(uint4*)&Ks[p ^ 1][(srow + 32) * LDK + scol] = kr1;
      *(uint4*)&Vs[p ^ 1][srow * LDK + scol] = vr0;
      *(uint4*)&Vs[p ^ 1][(srow + 32) * LDK + scol] = vr1;
    }
    p ^= 1;
  }

  // reduce row sums across the 16 lanes holding each row
#pragma unroll
  for (int r = 0; r < 4; r++)
#pragma unroll
    for (int off = 1; off < 16; off <<= 1) ls[r] += __shfl_xor(ls[r], off);

  if (!heavy) {
#pragma unroll
    for (int r = 0; r < 4; r++) {
      float inv = 1.f / ls[r];
      size_t row = (size_t)b * SS + (size_t)l * 64 + w * 16 + quad * 4 + r;
#pragma unroll
      for (int tt = 0; tt < 4; tt++)
        ctxb[row * DD + h * HD + tt * 16 + lr] = f2bf(Ot[tt][r] * inv);
    }
    return;
  }

  // ---- heavy: write partials, then last-arriving chunk reduces ----
  float* pb = part + ((size_t)hid * 8 + chunk) * 4160;  // 64*64 O + 64 lsum
#pragma unroll
  for (int r = 0; r < 4; r++) {
    int rowi = w * 16 + quad * 4 + r;
#pragma unroll
    for (int tt = 0; tt < 4; tt++) pb[rowi * 64 + tt * 16 + lr] = Ot[tt][r];
    if (lr == 0) pb[4096 + rowi] = ls[r];
  }
  __threadfence();   // release: partials visible device-wide
  __syncthreads();   // all threads of the block fenced
  if (tid == 0) isLast = (atomicAdd(&cnt[hid], 1) == 7);
  __syncthreads();
  if (isLast) {
    __threadfence();  // acquire: other chunks' partials visible
    float* lrow = (float*)&Ks[0][0];  // LDS reuse (compute fully done)
    const float* pbase = part + (size_t)hid * 8 * 4160;
    if (tid < 64) {
      float s = 0.f;
#pragma unroll
      for (int c = 0; c < 8; c++) s += pbase[c * 4160 + 4096 + tid];
      lrow[tid] = s;
    }
    __syncthreads();
    for (int e = tid; e < 4096; e += 256) {
      float o = 0.f;
#pragma unroll
      for (int c = 0; c < 8; c++) o += pbase[c * 4160 + e];
      int rowi = e >> 6, col = e & 63;
      size_t row = (size_t)b * SS + (size_t)l * 64 + rowi;
      ctxb[row * DD + h * HD + col] = f2bf(o / lrow[rowi]);
    }
  }
}

extern "C" void kernel_launch(void* const* d_in, const int* in_sizes, int n_in,
                              void* d_out, int out_size, void* d_ws,
                              size_t ws_size, hipStream_t stream) {
  const float* hs = (const float*)d_in[0];
  const float* Wq = (const float*)d_in[1];
  const float* Wk = (const float*)d_in[2];
  const float* Wv = (const float*)d_in[3];
  const float* Wo = (const float*)d_in[4];
  const int* graph = (const int*)d_in[10];

  const size_t NHS = (size_t)BB * SS * DD;  // 6291456
  unsigned short* hsb = (unsigned short*)d_ws;
  unsigned short* wqkvb = hsb + NHS;            // 3*768*768
  unsigned short* wob = wqkvb + 3 * 768 * 768;  // 768*768
  unsigned short* qb = wob + 768 * 768;
  unsigned short* kb = qb + NHS;
  unsigned short* vtb = kb + NHS;
  unsigned short* ctxb = vtb + NHS;
  float* part = (float*)(ctxb + NHS);       // 48*8*4160 floats
  int* cnt = (int*)(part + 48 * 8 * 4160);  // 48 ints

  cvt_all<<<8448, 256, 0, stream>>>(hs, Wq, Wk, Wv, Wo, hsb, wqkvb, wob, cnt);
  gemm_qkv_b<<<dim3(64, 36, 1), 256, 0, stream>>>(hsb, wqkvb, qb, kb, vtb);
  attn2r<<<1872, 256, 0, stream>>>(qb, kb, vtb, graph, ctxb, part, cnt);
  gemm_out_b<<<dim3(64, 12, 1), 256, 0, stream>>>(ctxb, wob, (float*)d_out);
}

// Round 10
// 203.904 us; speedup vs baseline: 1.7999x; 1.3519x over previous
//
#include <hip/hip_runtime.h>
#include <hip/hip_bf16.h>

#define BB 2
#define HH 12
#define SS 4096
#define DD 768
#define HD 64
#define NBK 64
#define MC 3
#define LDK 72   // K/V stride (proven)
#define LDKP 68  // Ps stride: 34*4 % 32 == 8 -> quads hit disjoint bank octets

typedef __attribute__((ext_vector_type(8))) short short8_t;
typedef __attribute__((ext_vector_type(4))) float float4_t;

__device__ __forceinline__ unsigned short f2bf(float f) {
  union { float f; unsigned u; } c;
  c.f = f;
  unsigned u = c.u + 0x7FFFu + ((c.u >> 16) & 1u);  // RNE
  return (unsigned short)(u >> 16);
}

// async 16B global -> LDS (gfx950). LDS dest = wave-uniform base + lane*16.
__device__ __forceinline__ void gload16(const unsigned short* gp,
                                        unsigned short* lp) {
  __builtin_amdgcn_global_load_lds(
      (const __attribute__((address_space(1))) unsigned int*)gp,
      (__attribute__((address_space(3))) unsigned int*)lp, 16, 0, 0);
}

// ---------------------------------------------------------------------------
// One-shot fp32 -> bf16 conversion (kept separate: round 8 proved inline
// conversion triples GEMM fetch traffic — bf16 staging pays for itself).
// ---------------------------------------------------------------------------
__global__ __launch_bounds__(256) void cvt_all(
    const float* __restrict__ hs, const float* __restrict__ Wq,
    const float* __restrict__ Wk, const float* __restrict__ Wv,
    const float* __restrict__ Wo, unsigned short* __restrict__ hsb,
    unsigned short* __restrict__ wqkvb, unsigned short* __restrict__ wob) {
  long i4 = (long)blockIdx.x * 256 + threadIdx.x;  // float4 index
  const float* src;
  unsigned short* dst;
  if (i4 < 1572864) {          // hs: 6291456 floats
    src = hs + i4 * 4;
    dst = hsb + i4 * 4;
  } else {
    long r = i4 - 1572864;
    int w = (int)(r / 147456);  // 0..3 : Wq,Wk,Wv,Wo (589824 floats each)
    long e = r % 147456;
    src = (w == 0 ? Wq : w == 1 ? Wk : w == 2 ? Wv : Wo) + e * 4;
    dst = (w < 3) ? (wqkvb + (long)w * 589824 + e * 4) : (wob + e * 4);
  }
  float4_t v = *(const float4_t*)src;
  uint2 p;
  p.x = (unsigned)f2bf(v[0]) | ((unsigned)f2bf(v[1]) << 16);
  p.y = (unsigned)f2bf(v[2]) | ((unsigned)f2bf(v[3]) << 16);
  *(uint2*)dst = p;
}

// ---------------------------------------------------------------------------
// GEMM (round-6 proven): BM=128 BN=64 BK=64, dbuf, 1 barrier/iter, XOR
// swizzle slot=c^(r&7) (measured 0 bank conflicts), gload_lds staging,
// 48 KB LDS -> 3 blocks/CU. Plain __launch_bounds__(256) (min-wave hints
// clamp VGPR below the accumulator and spill — rounds 2/3).
// ---------------------------------------------------------------------------
#define STAGE_T(buf_, A_, B_, m0_, n0_, kt_)                                  \
  {                                                                           \
    int rr_ = lane >> 3;                                                      \
    int cg_ = (lane & 7) ^ rr_;                                               \
    _Pragma("unroll") for (int u = 0; u < 4; u++) {                           \
      int g_ = w * 4 + u;                                                     \
      gload16(A_ + (size_t)(m0_ + g_ * 8 + rr_) * DD + kt_ + cg_ * 8,         \
              &As[buf_][g_ * 512]);                                           \
    }                                                                         \
    _Pragma("unroll") for (int u = 0; u < 2; u++) {                           \
      int g_ = w * 2 + u;                                                     \
      gload16(B_ + (size_t)(n0_ + g_ * 8 + rr_) * DD + kt_ + cg_ * 8,         \
              &Bs[buf_][g_ * 512]);                                           \
    }                                                                         \
  }

#define LOAD_FRAGS2(buf_, kk_)                                                \
  int cb = qd + ((kk_) >> 3);                                                 \
  short8_t af[2], bfr[4];                                                     \
  _Pragma("unroll") for (int i = 0; i < 2; i++) {                             \
    int r_ = wm + i * 16 + fr;                                                \
    af[i] = *(const short8_t*)&As[buf_][r_ * 64 + (cb ^ (fr & 7)) * 8];       \
  }                                                                           \
  _Pragma("unroll") for (int j = 0; j < 4; j++) {                             \
    int r_ = j * 16 + fr;                                                     \
    bfr[j] = *(const short8_t*)&Bs[buf_][r_ * 64 + (cb ^ (fr & 7)) * 8];      \
  }

__global__ __launch_bounds__(256) void gemm_qkv_b(
    const unsigned short* __restrict__ A, const unsigned short* __restrict__ W,
    unsigned short* __restrict__ qb, unsigned short* __restrict__ kb,
    unsigned short* __restrict__ vtb) {
  __shared__ unsigned short As[2][128 * 64];  // 32 KB
  __shared__ unsigned short Bs[2][64 * 64];   // 16 KB
  int tid = threadIdx.x;
  int m0 = blockIdx.x * 128;
  int n0 = blockIdx.y * 64;   // 64 | 768 so never straddles
  int lane = tid & 63;
  int w = tid >> 6;
  int wm = w * 32;            // 4 waves x 32 rows; all waves span 64 cols
  int fr = lane & 15;
  int qd = lane >> 4;
  int ysel = n0 / 768;

  float4_t acc[8];
#pragma unroll
  for (int i = 0; i < 8; i++)
#pragma unroll
    for (int r = 0; r < 4; r++) acc[i][r] = 0.f;

  STAGE_T(0, A, W, m0, n0, 0)
  int p = 0;

  if (ysel < 2) {
    // ---- Q/K: swapped-operand K-loop; acc[j*2+i] = C^T tile ----
    for (int kt = 0; kt < DD; kt += 64) {
      __syncthreads();  // drains stage(kt); waves done reading buf p^1
      if (kt + 64 < DD) STAGE_T(p ^ 1, A, W, m0, n0, kt + 64)
#pragma unroll
      for (int kk = 0; kk < 64; kk += 32) {
        LOAD_FRAGS2(p, kk)
#pragma unroll
        for (int i = 0; i < 2; i++)
#pragma unroll
          for (int j = 0; j < 4; j++)
            acc[j * 2 + i] = __builtin_amdgcn_mfma_f32_16x16x32_bf16(
                bfr[j], af[i], acc[j * 2 + i], 0, 0, 0);
      }
      p ^= 1;
    }
    int cn = lane & 15;
    int quad = lane >> 4;
    float scale = (ysel == 0) ? 0.125f : 1.0f;  // fold 1/sqrt(64) into Q
    unsigned short* dst = (ysel == 0) ? qb : kb;
    int nb0 = n0 - ysel * 768;
#pragma unroll
    for (int j = 0; j < 4; j++)
#pragma unroll
      for (int i = 0; i < 2; i++) {
        int m = m0 + wm + i * 16 + cn;         // s dimension
        int nn = nb0 + j * 16 + quad * 4;      // d dimension (4-consec)
        int b = m >> 12, s = m & 4095;
        int h = nn >> 6, d0 = nn & 63;
        uint2 pk;
        pk.x = (unsigned)f2bf(acc[j * 2 + i][0] * scale) |
               ((unsigned)f2bf(acc[j * 2 + i][1] * scale) << 16);
        pk.y = (unsigned)f2bf(acc[j * 2 + i][2] * scale) |
               ((unsigned)f2bf(acc[j * 2 + i][3] * scale) << 16);
        *(uint2*)&dst[(((size_t)b * HH + h) * SS + s) * HD + d0] = pk;
      }
  } else {
    // ---- V: normal K-loop; reg dim spans s (contig in [b][h][d][s]) ----
    for (int kt = 0; kt < DD; kt += 64) {
      __syncthreads();
      if (kt + 64 < DD) STAGE_T(p ^ 1, A, W, m0, n0, kt + 64)
#pragma unroll
      for (int kk = 0; kk < 64; kk += 32) {
        LOAD_FRAGS2(p, kk)
#pragma unroll
        for (int i = 0; i < 2; i++)
#pragma unroll
          for (int j = 0; j < 4; j++)
            acc[i * 4 + j] = __builtin_amdgcn_mfma_f32_16x16x32_bf16(
                af[i], bfr[j], acc[i * 4 + j], 0, 0, 0);
      }
      p ^= 1;
    }
    int cn = lane & 15;
    int quad = lane >> 4;
    int nb0 = n0 - 1536;
#pragma unroll
    for (int i = 0; i < 2; i++)
#pragma unroll
      for (int j = 0; j < 4; j++) {
        int m = m0 + wm + i * 16 + quad * 4;   // s base (4-consec)
        int nn = nb0 + j * 16 + cn;            // d dimension
        int b = m >> 12, s0 = m & 4095;
        int h = nn >> 6, d = nn & 63;
        uint2 pk;
        pk.x = (unsigned)f2bf(acc[i * 4 + j][0]) |
               ((unsigned)f2bf(acc[i * 4 + j][1]) << 16);
        pk.y = (unsigned)f2bf(acc[i * 4 + j][2]) |
               ((unsigned)f2bf(acc[i * 4 + j][3]) << 16);
        *(uint2*)&vtb[(((size_t)b * HH + h) * HD + d) * SS + s0] = pk;
      }
  }
}

__global__ __launch_bounds__(256) void gemm_out_b(
    const unsigned short* __restrict__ A, const unsigned short* __restrict__ W,
    float* __restrict__ dst) {
  __shared__ unsigned short As[2][128 * 64];
  __shared__ unsigned short Bs[2][64 * 64];
  int tid = threadIdx.x;
  int m0 = blockIdx.x * 128;
  int n0 = blockIdx.y * 64;
  int lane = tid & 63;
  int w = tid >> 6;
  int wm = w * 32;
  int fr = lane & 15;
  int qd = lane >> 4;

  float4_t acc[8];
#pragma unroll
  for (int i = 0; i < 8; i++)
#pragma unroll
    for (int r = 0; r < 4; r++) acc[i][r] = 0.f;

  STAGE_T(0, A, W, m0, n0, 0)
  int p = 0;
  for (int kt = 0; kt < DD; kt += 64) {
    __syncthreads();
    if (kt + 64 < DD) STAGE_T(p ^ 1, A, W, m0, n0, kt + 64)
#pragma unroll
    for (int kk = 0; kk < 64; kk += 32) {
      LOAD_FRAGS2(p, kk)
#pragma unroll
      for (int i = 0; i < 2; i++)
#pragma unroll
        for (int j = 0; j < 4; j++)
          acc[i * 4 + j] = __builtin_amdgcn_mfma_f32_16x16x32_bf16(
              af[i], bfr[j], acc[i * 4 + j], 0, 0, 0);
    }
    p ^= 1;
  }

  int cn = lane & 15;
  int rb = (lane >> 4) * 4;
#pragma unroll
  for (int i = 0; i < 2; i++)
#pragma unroll
    for (int j = 0; j < 4; j++)
#pragma unroll
      for (int r = 0; r < 4; r++) {
        int m = m0 + wm + i * 16 + rb + r;
        int n = n0 + j * 16 + cn;
        dst[(size_t)m * DD + n] = acc[i * 4 + j][r];
      }
}

// ---------------------------------------------------------------------------
// Block-sparse attention. XCD-aware id swizzle (1872 = 8*234, bijective):
// blocks sharing (b,h) — and thus K/V panels — land on the same XCD's L2,
// removing the 8x panel duplication (round-9 counter: 83 MB fetch vs 24 MB
// of data). Ps stride LDKP=68 kills the P-write quad bank conflicts.
// Heavy blocks (l=0,63) split 8 ways -> partial O + rowsum to scratch
// (separate reduce kernel: round 9 proved per-block __threadfence costs
// ~200ns each — never in the hot path).
// ---------------------------------------------------------------------------
__global__ __launch_bounds__(256) void attn2(
    const unsigned short* __restrict__ q, const unsigned short* __restrict__ k,
    const unsigned short* __restrict__ vt, const int* __restrict__ graph,
    unsigned short* __restrict__ ctxb, float* __restrict__ part) {
  __shared__ unsigned short Ks[2][64 * LDK];    // K[key][d]
  __shared__ unsigned short Vs[2][64 * LDK];    // V^T[d][key]
  __shared__ unsigned short Ps[4][16 * LDKP];   // per-wave P[q][key]

  int tid = threadIdx.x;
  // XCD swizzle: consecutive ids on one XCD (dispatch round-robins % 8)
  int id = (blockIdx.x & 7) * 234 + (blockIdx.x >> 3);
  int b, h, l, nkb, heavy, chunk = 0, hid = 0;
  int list[8];
  if (id < 384) {
    heavy = 1;
    hid = id >> 3;
    chunk = id & 7;
    b = hid / 24;
    int r = hid % 24;
    h = r >> 1;
    l = (r & 1) ? (NBK - 1) : 0;
    nkb = 8;
#pragma unroll
    for (int i = 0; i < 8; i++) list[i] = chunk * 8 + i;
  } else {
    heavy = 0;
    int j = id - 384;
    b = j / 744;  // 744 = 12*62
    int r = j % 744;
    h = r / 62;
    l = 1 + r % 62;
    const int* g = graph + (((size_t)b * HH + h) * NBK + l) * MC;
    int n = 0;
    if (l == 1) {
      list[0] = 0; list[1] = 1; list[2] = 2; list[3] = NBK - 1; n = 4;
    } else if (l == NBK - 2) {
      list[0] = 0; list[1] = NBK - 3; list[2] = NBK - 2; list[3] = NBK - 1;
      n = 4;
    } else {
      list[0] = 0; list[1] = l - 1; list[2] = l; list[3] = l + 1;
      list[4] = NBK - 1; n = 5;
    }
    for (int m = 0; m < MC; m++) list[n++] = g[m];
    nkb = n;
  }
  size_t base = ((size_t)b * HH + h) * SS * HD;

  int lane = tid & 63;
  int w = tid >> 6;
  int lr = lane & 15;     // fragment m/n index
  int quad = lane >> 4;   // fragment k-group

  // Q fragments (A-layout) straight from global (q pre-scaled).
  short8_t qa[2];
  {
    const unsigned short* qp =
        q + base + (size_t)(l * 64 + w * 16 + lr) * HD + quad * 8;
    qa[0] = *(const short8_t*)qp;
    qa[1] = *(const short8_t*)(qp + 32);
  }

  float4_t Ot[4];
  float ls[4];
#pragma unroll
  for (int t = 0; t < 4; t++)
#pragma unroll
    for (int r = 0; r < 4; r++) Ot[t][r] = 0.f;
#pragma unroll
  for (int r = 0; r < 4; r++) ls[r] = 0.f;

  // staging: each thread moves 2x16B for K and 2x16B for Vt
  int srow = tid >> 3;          // 0..31
  int scol = (tid & 7) * 8;     // 0..56

  uint4 kr0, kr1, vr0, vr1;
  {
    int kb = list[0];
    const unsigned short* kp = k + base + (size_t)(kb * 64 + srow) * HD + scol;
    const unsigned short* vp = vt + base + (size_t)srow * SS + kb * 64 + scol;
    kr0 = *(const uint4*)kp;
    kr1 = *(const uint4*)(kp + 32 * HD);
    vr0 = *(const uint4*)vp;
    vr1 = *(const uint4*)(vp + 32 * SS);
  }
  *(uint4*)&Ks[0][srow * LDK + scol] = kr0;
  *(uint4*)&Ks[0][(srow + 32) * LDK + scol] = kr1;
  *(uint4*)&Vs[0][srow * LDK + scol] = vr0;
  *(uint4*)&Vs[0][(srow + 32) * LDK + scol] = vr1;
  int p = 0;

  for (int t = 0; t < nkb; t++) {
    __syncthreads();  // buf[p] writes visible; all waves done reading buf[p^1]

    if (t + 1 < nkb) {  // issue next block's global loads (fly during compute)
      int kb = list[t + 1];
      const unsigned short* kp =
          k + base + (size_t)(kb * 64 + srow) * HD + scol;
      const unsigned short* vp =
          vt + base + (size_t)srow * SS + kb * 64 + scol;
      kr0 = *(const uint4*)kp;
      kr1 = *(const uint4*)(kp + 32 * HD);
      vr0 = *(const uint4*)vp;
      vr1 = *(const uint4*)(vp + 32 * SS);
    }

    // S = Q K^T
    float4_t st[4];
#pragma unroll
    for (int tt = 0; tt < 4; tt++) {
#pragma unroll
      for (int r = 0; r < 4; r++) st[tt][r] = 0.f;
      short8_t kb0 = *(const short8_t*)&Ks[p][(tt * 16 + lr) * LDK + quad * 8];
      short8_t kb1 =
          *(const short8_t*)&Ks[p][(tt * 16 + lr) * LDK + quad * 8 + 32];
      st[tt] =
          __builtin_amdgcn_mfma_f32_16x16x32_bf16(qa[0], kb0, st[tt], 0, 0, 0);
      st[tt] =
          __builtin_amdgcn_mfma_f32_16x16x32_bf16(qa[1], kb1, st[tt], 0, 0, 0);
    }

    // fixed-max softmax: p = exp(s); per-lane partial sums, no shuffles.
#pragma unroll
    for (int tt = 0; tt < 4; tt++)
#pragma unroll
      for (int r = 0; r < 4; r++) {
        float pv = __expf(st[tt][r]);
        st[tt][r] = pv;
        ls[r] += pv;
        Ps[w][(quad * 4 + r) * LDKP + tt * 16 + lr] = f2bf(pv);
      }

    // O += P V
#pragma unroll
    for (int s = 0; s < 2; s++) {
      short8_t pa = *(const short8_t*)&Ps[w][lr * LDKP + s * 32 + quad * 8];
#pragma unroll
      for (int tt = 0; tt < 4; tt++) {
        short8_t vb =
            *(const short8_t*)&Vs[p][(tt * 16 + lr) * LDK + s * 32 + quad * 8];
        Ot[tt] =
            __builtin_amdgcn_mfma_f32_16x16x32_bf16(pa, vb, Ot[tt], 0, 0, 0);
      }
    }

    if (t + 1 < nkb) {  // write prefetched regs into the other buffer
      *(uint4*)&Ks[p ^ 1][srow * LDK + scol] = kr0;
      *(uint4*)&Ks[p ^ 1][(srow + 32) * LDK + scol] = kr1;
      *(uint4*)&Vs[p ^ 1][srow * LDK + scol] = vr0;
      *(uint4*)&Vs[p ^ 1][(srow + 32) * LDK + scol] = vr1;
    }
    p ^= 1;
  }

  // reduce row sums across the 16 lanes holding each row
#pragma unroll
  for (int r = 0; r < 4; r++)
#pragma unroll
    for (int off = 1; off < 16; off <<= 1) ls[r] += __shfl_xor(ls[r], off);

  if (!heavy) {
#pragma unroll
    for (int r = 0; r < 4; r++) {
      float inv = 1.f / ls[r];
      size_t row = (size_t)b * SS + (size_t)l * 64 + w * 16 + quad * 4 + r;
#pragma unroll
      for (int tt = 0; tt < 4; tt++)
        ctxb[row * DD + h * HD + tt * 16 + lr] = f2bf(Ot[tt][r] * inv);
    }
  } else {
    float* pb = part + ((size_t)hid * 8 + chunk) * 4160;  // 64*64 O + 64 lsum
#pragma unroll
    for (int r = 0; r < 4; r++) {
      int rowi = w * 16 + quad * 4 + r;
#pragma unroll
      for (int tt = 0; tt < 4; tt++)
        pb[rowi * 64 + tt * 16 + lr] = Ot[tt][r];
      if (lr == 0) pb[4096 + rowi] = ls[r];
    }
  }
}

// ---------------------------------------------------------------------------
// Combine the 8 partials of each heavy block, normalize, write bf16 ctx.
// ---------------------------------------------------------------------------
__global__ __launch_bounds__(256) void reduce_heavy(
    const float* __restrict__ part, unsigned short* __restrict__ ctxb) {
  __shared__ float lrow[64];
  int hid = blockIdx.x;
  int tid = threadIdx.x;
  int b = hid / 24;
  int r = hid % 24;
  int h = r >> 1;
  int l = (r & 1) ? (NBK - 1) : 0;
  const float* pb = part + (size_t)hid * 8 * 4160;
  if (tid < 64) {
    float s = 0.f;
#pragma unroll
    for (int c = 0; c < 8; c++) s += pb[c * 4160 + 4096 + tid];
    lrow[tid] = s;
  }
  __syncthreads();
#pragma unroll
  for (int e = tid; e < 4096; e += 256) {
    float o = 0.f;
#pragma unroll
    for (int c = 0; c < 8; c++) o += pb[c * 4160 + e];
    int rowi = e >> 6, col = e & 63;
    size_t row = (size_t)b * SS + (size_t)l * 64 + rowi;
    ctxb[row * DD + h * HD + col] = f2bf(o / lrow[rowi]);
  }
}

extern "C" void kernel_launch(void* const* d_in, const int* in_sizes, int n_in,
                              void* d_out, int out_size, void* d_ws,
                              size_t ws_size, hipStream_t stream) {
  const float* hs = (const float*)d_in[0];
  const float* Wq = (const float*)d_in[1];
  const float* Wk = (const float*)d_in[2];
  const float* Wv = (const float*)d_in[3];
  const float* Wo = (const float*)d_in[4];
  const int* graph = (const int*)d_in[10];

  const size_t NHS = (size_t)BB * SS * DD;  // 6291456
  unsigned short* hsb = (unsigned short*)d_ws;
  unsigned short* wqkvb = hsb + NHS;            // 3*768*768
  unsigned short* wob = wqkvb + 3 * 768 * 768;  // 768*768
  unsigned short* qb = wob + 768 * 768;
  unsigned short* kb = qb + NHS;
  unsigned short* vtb = kb + NHS;
  unsigned short* ctxb = vtb + NHS;
  float* part = (float*)(ctxb + NHS);  // 48*8*4160 floats

  cvt_all<<<8448, 256, 0, stream>>>(hs, Wq, Wk, Wv, Wo, hsb, wqkvb, wob);
  gemm_qkv_b<<<dim3(64, 36, 1), 256, 0, stream>>>(hsb, wqkvb, qb, kb, vtb);
  attn2<<<1872, 256, 0, stream>>>(qb, kb, vtb, graph, ctxb, part);
  reduce_heavy<<<48, 256, 0, stream>>>(part, ctxb);
  gemm_out_b<<<dim3(64, 12, 1), 256, 0, stream>>>(ctxb, wob, (float*)d_out);
}